// Round 1
// baseline (38557.797 us; speedup 1.0000x reference)
//
#include <hip/hip_runtime.h>
#include <cmath>
#include <complex>
#include <algorithm>

#define NPATH   11
#define NNODES  10000
#define NEDGES  160000
#define ETILE   16
#define INDIM   144

struct TPConsts { float coef[363]; };

// ---------------- host: exact port of reference Wigner-3j construction ----------------
static double factd(int n){ double r = 1.0; for (int i = 2; i <= n; ++i) r *= (double)i; return r; }

static double su2_cg(int j1,int m1,int j2,int m2,int j3,int m3){
  if (m3 != m1 + m2) return 0.0;
  int vmin = std::max(std::max(-j1 + j2 + m3, -j1 + m1), 0);
  int vmax = std::min(std::min(j2 + j3 + m1, j3 - j1 + j2), j3 + m3);
  double C = std::sqrt((2.0*j3 + 1.0)
      * factd(j3 + j1 - j2) * factd(j3 - j1 + j2) * factd(j1 + j2 - j3) / factd(j1 + j2 + j3 + 1)
      * factd(j3 + m3) * factd(j3 - m3)
      / (factd(j1 - m1) * factd(j1 + m1) * factd(j2 - m2) * factd(j2 + m2)));
  double S = 0.0;
  for (int v = vmin; v <= vmax; ++v){
    double sgn = ((v + j2 + m2) & 1) ? -1.0 : 1.0;
    S += sgn / factd(v) * factd(j2 + j3 + m1 - v) * factd(j1 - m1 + v)
         / factd(j3 - j1 + j2 - v) / factd(j3 + m3 - v) / factd(v + j1 - j2 - m3);
  }
  return C * S;
}

static void qmat(int l, std::complex<double>* q){
  int n = 2*l + 1;
  for (int i = 0; i < n*n; ++i) q[i] = 0.0;
  const double is2 = 1.0 / std::sqrt(2.0);
  const std::complex<double> I(0.0, 1.0);
  for (int m = -l; m < 0; ++m){
    q[(l+m)*n + (l-m)] = is2;        // l + |m|
    q[(l+m)*n + (l+m)] = -I * is2;   // l - |m|
  }
  q[l*n + l] = 1.0;
  for (int m = 1; m <= l; ++m){
    double sgn = (m & 1) ? -1.0 : 1.0;
    q[(l+m)*n + (l+m)] = sgn * is2;
    q[(l+m)*n + (l-m)] = I * sgn * is2;
  }
  std::complex<double> ph(1.0, 0.0);
  for (int i = 0; i < l; ++i) ph *= std::complex<double>(0.0, -1.0);  // (-1j)^l
  for (int i = 0; i < n*n; ++i) q[i] *= ph;
}

static void w3j_tensor(int l1,int l2,int l3, double* out){
  int n1 = 2*l1+1, n2 = 2*l2+1, n3 = 2*l3+1;
  std::complex<double> C[125];
  for (int a = 0; a < n1; ++a)
    for (int b = 0; b < n2; ++b)
      for (int c = 0; c < n3; ++c)
        C[(a*n2 + b)*n3 + c] = su2_cg(l1, a - l1, l2, b - l2, l3, c - l3);
  std::complex<double> q1[25], q2[25], q3[25];
  qmat(l1, q1); qmat(l2, q2); qmat(l3, q3);
  double norm = 0.0;
  // Cr[j,l,m] = Re( sum_{i,k,n} q1[i,j] q2[k,l] conj(q3[n,m]) C[i,k,n] )
  for (int j = 0; j < n1; ++j)
    for (int lq = 0; lq < n2; ++lq)
      for (int m = 0; m < n3; ++m){
        std::complex<double> s(0.0, 0.0);
        for (int i = 0; i < n1; ++i)
          for (int k = 0; k < n2; ++k)
            for (int nn = 0; nn < n3; ++nn)
              s += q1[i*n1 + j] * q2[k*n2 + lq] * std::conj(q3[nn*n3 + m]) * C[(i*n2 + k)*n3 + nn];
        double v = s.real();
        out[(j*n2 + lq)*n3 + m] = v;
        norm += v * v;
      }
  norm = std::sqrt(norm);
  for (int i = 0; i < n1*n2*n3; ++i) out[i] /= norm;
}

static TPConsts build_consts(){
  TPConsts K;
  const int PL1[NPATH] = {0,0,0,1,1,1,1,2,2,2,2};
  const int PL2[NPATH] = {0,1,2,0,1,1,2,0,1,2,2};
  const int PL3[NPATH] = {0,1,2,1,0,2,1,2,1,0,2};
  const double FAN[3]  = {48.0, 64.0, 64.0};
  double buf[125];
  int off = 0;
  for (int p = 0; p < NPATH; ++p){
    int l1 = PL1[p], l2 = PL2[p], l3 = PL3[p];
    int n = (2*l1+1)*(2*l2+1)*(2*l3+1);
    w3j_tensor(l1, l2, l3, buf);
    double alpha = std::sqrt((double)(2*l3+1)) / std::sqrt(FAN[l3]);
    for (int i = 0; i < n; ++i) K.coef[off + i] = (float)(buf[i] * alpha);
    off += n;
  }
  return K;
}

// ---------------- device ----------------
__device__ __forceinline__ float silu_f(float v){ return v / (1.0f + expf(-v)); }

__global__ __launch_bounds__(256)
void e3conv_edge_kernel(TPConsts K,
    const float* __restrict__ f_in, const float* __restrict__ pos,
    const int*   __restrict__ batch,
    const int*   __restrict__ esrc, const int* __restrict__ edst,
    const float* __restrict__ eshift, const float* __restrict__ cell,
    const float* __restrict__ w0, const float* __restrict__ b0,
    const float* __restrict__ w1, const float* __restrict__ b1,
    const float* __restrict__ w2, const float* __restrict__ b2,
    const float* __restrict__ w3, const float* __restrict__ b3,
    float* __restrict__ out, float* __restrict__ cnt)
{
  __shared__ float s_sh [ETILE][9];
  __shared__ float s_emb[ETILE][8];
  __shared__ float s_x1 [ETILE][INDIM];
  __shared__ float s_hA [ETILE][65];   // +1 pad: conflict-free broadcast reads in phase D
  __shared__ float s_hB [ETILE][65];
  __shared__ float s_tmp[ETILE][35*16];
  __shared__ int   s_src[ETILE];
  __shared__ int   s_dst[ETILE];

  const int t = threadIdx.x;

  // ---- Phase A: per-edge geometry, spherical harmonics, radial basis ----
  if (t < ETILE){
    const int eg  = blockIdx.x * ETILE + t;
    const int src = esrc[eg];
    const int dst = edst[eg];
    s_src[t] = src; s_dst[t] = dst;
    const int g = batch[src];
    const float sx = eshift[eg*3+0], sy = eshift[eg*3+1], sz = eshift[eg*3+2];
    const float* cg = cell + g*9;
    float vx = pos[dst*3+0] - pos[src*3+0] + sx*cg[0] + sy*cg[3] + sz*cg[6];
    float vy = pos[dst*3+1] - pos[src*3+1] + sx*cg[1] + sy*cg[4] + sz*cg[7];
    float vz = pos[dst*3+2] - pos[src*3+2] + sx*cg[2] + sy*cg[5] + sz*cg[8];
    float r  = sqrtf(vx*vx + vy*vy + vz*vz + 1e-12f);
    float inv = 1.0f / r;
    float x = vx*inv, y = vy*inv, z = vz*inv;
    const float s3 = 1.7320508075688772f, s5 = 2.23606797749979f, s15 = 3.872983346207417f;
    s_sh[t][0] = 1.0f;
    s_sh[t][1] = s3 * y;
    s_sh[t][2] = s3 * z;
    s_sh[t][3] = s3 * x;
    s_sh[t][4] = s15 * x * y;
    s_sh[t][5] = s15 * y * z;
    s_sh[t][6] = 0.5f * s5 * (3.0f*z*z - 1.0f);
    s_sh[t][7] = s15 * x * z;
    s_sh[t][8] = 0.5f * s15 * (x*x - y*y);
    float xr   = fminf(fmaxf(r * (1.0f/6.0f), 0.0f), 1.0f);
    float mask = (r <= 6.0f) ? 2.8284271247461903f : 0.0f;  // sqrt(8) * (r<=R_MAX)
    #pragma unroll
    for (int b = 0; b < 8; ++b){
      float d = (xr - (float)b * (1.0f/7.0f)) * 7.0f;
      s_emb[t][b] = mask * expf(-0.5f * d * d);
    }
    atomicAdd(&cnt[dst], 1.0f);
  }
  __syncthreads();

  // ---- gather f_in[src] tiles ----
  for (int idx = t; idx < ETILE*INDIM; idx += 256){
    int e = idx / INDIM;
    int c = idx - e*INDIM;
    s_x1[e][c] = f_in[s_src[e]*INDIM + c];
  }

  // ---- Phase B: MLP 8 -> 64 -> 64 -> 64 ----
  #pragma unroll
  for (int it = 0; it < 4; ++it){
    int idx = t + it*256;
    int e = idx >> 6, o = idx & 63;
    float s = b0[o];
    #pragma unroll
    for (int c = 0; c < 8; ++c) s = fmaf(s_emb[e][c], w0[c*64 + o], s);
    s_hA[e][o] = silu_f(s);
  }
  __syncthreads();
  #pragma unroll
  for (int it = 0; it < 4; ++it){
    int idx = t + it*256;
    int e = idx >> 6, o = idx & 63;
    float s = b1[o];
    for (int c = 0; c < 64; ++c) s = fmaf(s_hA[e][c], w1[c*64 + o], s);
    s_hB[e][o] = silu_f(s);
  }
  __syncthreads();
  #pragma unroll
  for (int it = 0; it < 4; ++it){
    int idx = t + it*256;
    int e = idx >> 6, o = idx & 63;
    float s = b2[o];
    for (int c = 0; c < 64; ++c) s = fmaf(s_hB[e][c], w2[c*64 + o], s);
    s_hA[e][o] = silu_f(s);
  }
  __syncthreads();

  // ---- Phase C: CG contraction tmp[e][s][u] = sum_{i,j} alpha*W3J[i,j,k] * x1[i,u] * sh[j] ----
  {
    const int ee = t >> 4;
    const int u  = t & 15;
    constexpr int PL1a[NPATH] = {0,0,0,1,1,1,1,2,2,2,2};
    constexpr int PL2a[NPATH] = {0,1,2,0,1,1,2,0,1,2,2};
    constexpr int PL3a[NPATH] = {0,1,2,1,0,2,1,2,1,0,2};
    constexpr int COFF[NPATH] = {0,1,10,35,44,53,98,143,168,213,238};
    constexpr int SB  [NPATH] = {0,1,4,9,12,13,18,21,26,29,30};
    constexpr int XOFF[NPATH] = {0,0,0,16,16,16,16,64,64,64,64};
    constexpr int SHO [NPATH] = {0,1,4,0,1,1,4,0,1,4,4};
    #pragma unroll
    for (int p = 0; p < NPATH; ++p){
      const int D1 = 2*PL1a[p]+1, D2 = 2*PL2a[p]+1, D3 = 2*PL3a[p]+1;
      float a[5];
      #pragma unroll
      for (int k = 0; k < D3; ++k) a[k] = 0.0f;
      #pragma unroll
      for (int i = 0; i < D1; ++i){
        const float xv = s_x1[ee][XOFF[p] + i*16 + u];
        #pragma unroll
        for (int j = 0; j < D2; ++j){
          const float xs = xv * s_sh[ee][SHO[p] + j];
          #pragma unroll
          for (int k = 0; k < D3; ++k)
            a[k] = fmaf(K.coef[COFF[p] + (i*D2 + j)*D3 + k], xs, a[k]);
        }
      }
      #pragma unroll
      for (int k = 0; k < D3; ++k) s_tmp[ee][(SB[p] + k)*16 + u] = a[k];
    }
  }
  __syncthreads();

  // ---- Phase D: fused weight-GEMM (h @ w3 + b3) + TP consume, per path ----
  {
    const int e  = t >> 4;
    const int wi = t & 15;
    constexpr int PL3a[NPATH] = {0,1,2,1,0,2,1,2,1,0,2};
    constexpr int SB  [NPATH] = {0,1,4,9,12,13,18,21,26,29,30};
    constexpr int QB  [NPATH] = {0,1,4,1,0,4,1,4,1,0,4};

    float acc[9];
    #pragma unroll
    for (int q = 0; q < 9; ++q) acc[q] = 0.0f;

    #pragma unroll
    for (int p = 0; p < NPATH; ++p){
      const int base = p*256 + wi;
      float wreg[16];
      #pragma unroll
      for (int u = 0; u < 16; ++u) wreg[u] = b3[base + u*16];
      const float* wp = w3 + base;
      for (int c = 0; c < 64; ++c){
        const float hc = s_hA[e][c];
        const float* row = wp + c*2816;
        #pragma unroll
        for (int u = 0; u < 16; ++u) wreg[u] = fmaf(hc, row[u*16], wreg[u]);
      }
      const int d3 = 2*PL3a[p] + 1;
      #pragma unroll
      for (int k = 0; k < d3; ++k){
        float s = 0.0f;
        const float* tp = &s_tmp[e][(SB[p] + k)*16];
        #pragma unroll
        for (int u = 0; u < 16; ++u) s = fmaf(tp[u], wreg[u], s);
        acc[QB[p] + k] += s;
      }
    }

    // ---- scatter: atomic accumulate into out[dst] ----
    const int dst = s_dst[e];
    float* op = out + dst*INDIM + wi;
    #pragma unroll
    for (int q = 0; q < 9; ++q) atomicAdd(op + q*16, acc[q]);
  }
}

__global__ __launch_bounds__(256)
void e3_div_kernel(float* __restrict__ out, const float* __restrict__ cnt, int n){
  int i = blockIdx.x * 256 + threadIdx.x;
  if (i < n){
    float c = cnt[i / INDIM];
    out[i] /= fmaxf(c, 1.0f);
  }
}

extern "C" void kernel_launch(void* const* d_in, const int* in_sizes, int n_in,
                              void* d_out, int out_size, void* d_ws, size_t ws_size,
                              hipStream_t stream)
{
  const float* f_in   = (const float*)d_in[0];
  const float* pos    = (const float*)d_in[1];
  // d_in[2] = A (unused by reference output)
  const int*   batch  = (const int*)  d_in[3];
  const int*   esrc   = (const int*)  d_in[4];
  const int*   edst   = (const int*)  d_in[5];
  const float* eshift = (const float*)d_in[6];
  const float* cell   = (const float*)d_in[7];
  const float* w0 = (const float*)d_in[8];  const float* b0 = (const float*)d_in[9];
  const float* w1 = (const float*)d_in[10]; const float* b1 = (const float*)d_in[11];
  const float* w2 = (const float*)d_in[12]; const float* b2 = (const float*)d_in[13];
  const float* w3 = (const float*)d_in[14]; const float* b3 = (const float*)d_in[15];
  float* out = (float*)d_out;
  float* cnt = (float*)d_ws;   // NNODES floats

  TPConsts K = build_consts();  // deterministic, host-side, captured by value in kernarg

  hipMemsetAsync(d_out, 0, (size_t)out_size * sizeof(float), stream);
  hipMemsetAsync(cnt, 0, (size_t)NNODES * sizeof(float), stream);

  e3conv_edge_kernel<<<NEDGES/ETILE, 256, 0, stream>>>(K,
      f_in, pos, batch, esrc, edst, eshift, cell,
      w0, b0, w1, b1, w2, b2, w3, b3, out, cnt);

  e3_div_kernel<<<(out_size + 255)/256, 256, 0, stream>>>(out, cnt, out_size);
}

// Round 2
// 2065.873 us; speedup vs baseline: 18.6642x; 18.6642x over previous
//
#include <hip/hip_runtime.h>
#include <cmath>
#include <complex>
#include <algorithm>

#define NPATH   11
#define NNODES  10000
#define NEDGES  160000
#define EB      32
#define INDIM   144

struct TPConsts { float coef[363]; };

// ---------------- host: exact port of reference Wigner-3j construction ----------------
static double factd(int n){ double r = 1.0; for (int i = 2; i <= n; ++i) r *= (double)i; return r; }

static double su2_cg(int j1,int m1,int j2,int m2,int j3,int m3){
  if (m3 != m1 + m2) return 0.0;
  int vmin = std::max(std::max(-j1 + j2 + m3, -j1 + m1), 0);
  int vmax = std::min(std::min(j2 + j3 + m1, j3 - j1 + j2), j3 + m3);
  double C = std::sqrt((2.0*j3 + 1.0)
      * factd(j3 + j1 - j2) * factd(j3 - j1 + j2) * factd(j1 + j2 - j3) / factd(j1 + j2 + j3 + 1)
      * factd(j3 + m3) * factd(j3 - m3)
      / (factd(j1 - m1) * factd(j1 + m1) * factd(j2 - m2) * factd(j2 + m2)));
  double S = 0.0;
  for (int v = vmin; v <= vmax; ++v){
    double sgn = ((v + j2 + m2) & 1) ? -1.0 : 1.0;
    S += sgn / factd(v) * factd(j2 + j3 + m1 - v) * factd(j1 - m1 + v)
         / factd(j3 - j1 + j2 - v) / factd(j3 + m3 - v) / factd(v + j1 - j2 - m3);
  }
  return C * S;
}

static void qmat(int l, std::complex<double>* q){
  int n = 2*l + 1;
  for (int i = 0; i < n*n; ++i) q[i] = 0.0;
  const double is2 = 1.0 / std::sqrt(2.0);
  const std::complex<double> I(0.0, 1.0);
  for (int m = -l; m < 0; ++m){
    q[(l+m)*n + (l-m)] = is2;
    q[(l+m)*n + (l+m)] = -I * is2;
  }
  q[l*n + l] = 1.0;
  for (int m = 1; m <= l; ++m){
    double sgn = (m & 1) ? -1.0 : 1.0;
    q[(l+m)*n + (l+m)] = sgn * is2;
    q[(l+m)*n + (l-m)] = I * sgn * is2;
  }
  std::complex<double> ph(1.0, 0.0);
  for (int i = 0; i < l; ++i) ph *= std::complex<double>(0.0, -1.0);
  for (int i = 0; i < n*n; ++i) q[i] *= ph;
}

static void w3j_tensor(int l1,int l2,int l3, double* out){
  int n1 = 2*l1+1, n2 = 2*l2+1, n3 = 2*l3+1;
  std::complex<double> C[125];
  for (int a = 0; a < n1; ++a)
    for (int b = 0; b < n2; ++b)
      for (int c = 0; c < n3; ++c)
        C[(a*n2 + b)*n3 + c] = su2_cg(l1, a - l1, l2, b - l2, l3, c - l3);
  std::complex<double> q1[25], q2[25], q3[25];
  qmat(l1, q1); qmat(l2, q2); qmat(l3, q3);
  double norm = 0.0;
  for (int j = 0; j < n1; ++j)
    for (int lq = 0; lq < n2; ++lq)
      for (int m = 0; m < n3; ++m){
        std::complex<double> s(0.0, 0.0);
        for (int i = 0; i < n1; ++i)
          for (int k = 0; k < n2; ++k)
            for (int nn = 0; nn < n3; ++nn)
              s += q1[i*n1 + j] * q2[k*n2 + lq] * std::conj(q3[nn*n3 + m]) * C[(i*n2 + k)*n3 + nn];
        double v = s.real();
        out[(j*n2 + lq)*n3 + m] = v;
        norm += v * v;
      }
  norm = std::sqrt(norm);
  for (int i = 0; i < n1*n2*n3; ++i) out[i] /= norm;
}

static TPConsts build_consts(){
  TPConsts K;
  const int PL1[NPATH] = {0,0,0,1,1,1,1,2,2,2,2};
  const int PL2[NPATH] = {0,1,2,0,1,1,2,0,1,2,2};
  const int PL3[NPATH] = {0,1,2,1,0,2,1,2,1,0,2};
  const double FAN[3]  = {48.0, 64.0, 64.0};
  double buf[125];
  int off = 0;
  for (int p = 0; p < NPATH; ++p){
    int l1 = PL1[p], l2 = PL2[p], l3 = PL3[p];
    int n = (2*l1+1)*(2*l2+1)*(2*l3+1);
    w3j_tensor(l1, l2, l3, buf);
    double alpha = std::sqrt((double)(2*l3+1)) / std::sqrt(FAN[l3]);
    for (int i = 0; i < n; ++i) K.coef[off + i] = (float)(buf[i] * alpha);
    off += n;
  }
  return K;
}

// ---------------- device ----------------
__device__ __forceinline__ float silu_f(float v){ return v / (1.0f + expf(-v)); }

// LDS float offsets
#define O_X1   0        // [32][144]
#define O_SH   4608     // [32][12]
#define O_HA   4992     // [32][65]
#define O_HT   7072     // [64][32]   h-final transposed [c][e]
#define O_TP   9120     // [32][80]   tmp: [e][k*16+u]
#define O_W    11680    // [32][256]  W tile [e][w*16+u]; aliases emb/hB/msg
#define O_EMB  11680    // [32][8]
#define O_HB   (11680+256) // [32][65]
#define O_SD   19872    // src[32], dst[32] (ints)
#define S_TOT  19936

// One path: tmp (CG contract) -> W-gen (h @ w3 slice) -> consume into acc.
// All shape params are template ints so every array index is compile-time.
template<int P,int D1,int D2,int D3,int QB,int COFF,int XOFF,int SHO>
__device__ __forceinline__ void path_step(
    const TPConsts& K, float* S,
    const float* __restrict__ w3, const float* __restrict__ b3,
    float (&acc)[9][2])
{
  const int t  = threadIdx.x;
  // ---- tmp_p: [32 e][D3 k][16 u] ----
  for (int s = t; s < 512; s += 256){
    const int te = s >> 4, u = s & 15;
    float a[D3];
    #pragma unroll
    for (int k = 0; k < D3; ++k) a[k] = 0.0f;
    #pragma unroll
    for (int i = 0; i < D1; ++i){
      const float xv = S[O_X1 + te*144 + XOFF + i*16 + u];
      #pragma unroll
      for (int j = 0; j < D2; ++j){
        const float xs = xv * S[O_SH + te*12 + SHO + j];
        #pragma unroll
        for (int k = 0; k < D3; ++k)
          a[k] = fmaf(K.coef[COFF + (i*D2 + j)*D3 + k], xs, a[k]);
      }
    }
    #pragma unroll
    for (int k = 0; k < D3; ++k) S[O_TP + te*80 + k*16 + u] = a[k];
  }
  __syncthreads();

  // ---- W-gen: wave e4 owns edges e4*8..+8, lane nq owns cols nq*4..+4 ----
  {
    const int e4 = t >> 6;          // wave id
    const int nq = t & 63;
    float wacc[8][4];
    {
      const float4 bv = *(const float4*)(b3 + P*256 + nq*4);
      #pragma unroll
      for (int e = 0; e < 8; ++e){
        wacc[e][0]=bv.x; wacc[e][1]=bv.y; wacc[e][2]=bv.z; wacc[e][3]=bv.w;
      }
    }
    const float* wbase = w3 + (size_t)P*256 + nq*4;
    #pragma unroll 4
    for (int c = 0; c < 64; ++c){
      const float4 wv = *(const float4*)(wbase + (size_t)c*2816);
      const float4 h0 = *(const float4*)(S + O_HT + c*32 + e4*8);
      const float4 h1 = *(const float4*)(S + O_HT + c*32 + e4*8 + 4);
      const float he[8] = {h0.x,h0.y,h0.z,h0.w,h1.x,h1.y,h1.z,h1.w};
      #pragma unroll
      for (int e = 0; e < 8; ++e){
        wacc[e][0] = fmaf(he[e], wv.x, wacc[e][0]);
        wacc[e][1] = fmaf(he[e], wv.y, wacc[e][1]);
        wacc[e][2] = fmaf(he[e], wv.z, wacc[e][2]);
        wacc[e][3] = fmaf(he[e], wv.w, wacc[e][3]);
      }
    }
    // store as [e][w*16 + u] so consume reads u-contiguous
    #pragma unroll
    for (int e = 0; e < 8; ++e){
      const int erow = O_W + (e4*8 + e)*256;
      #pragma unroll
      for (int j = 0; j < 4; ++j){
        const int n = nq*4 + j;          // n = u*16 + w
        S[erow + (n & 15)*16 + (n >> 4)] = wacc[e][j];
      }
    }
  }
  __syncthreads();

  // ---- consume: thread (e = t>>3, w2 = t&7) handles w ∈ {w2, w2+8} ----
  {
    const int e_c = t >> 3;
    const int w2  = t & 7;
    float wr0[16], wr1[16];
    #pragma unroll
    for (int q = 0; q < 4; ++q){
      const float4 v0 = *(const float4*)(S + O_W + e_c*256 + (w2    )*16 + q*4);
      const float4 v1 = *(const float4*)(S + O_W + e_c*256 + (w2 + 8)*16 + q*4);
      wr0[q*4+0]=v0.x; wr0[q*4+1]=v0.y; wr0[q*4+2]=v0.z; wr0[q*4+3]=v0.w;
      wr1[q*4+0]=v1.x; wr1[q*4+1]=v1.y; wr1[q*4+2]=v1.z; wr1[q*4+3]=v1.w;
    }
    #pragma unroll
    for (int k = 0; k < D3; ++k){
      float s0 = 0.0f, s1 = 0.0f;
      #pragma unroll
      for (int q = 0; q < 4; ++q){
        const float4 tv = *(const float4*)(S + O_TP + e_c*80 + k*16 + q*4);
        s0 = fmaf(tv.x, wr0[q*4+0], s0); s1 = fmaf(tv.x, wr1[q*4+0], s1);
        s0 = fmaf(tv.y, wr0[q*4+1], s0); s1 = fmaf(tv.y, wr1[q*4+1], s1);
        s0 = fmaf(tv.z, wr0[q*4+2], s0); s1 = fmaf(tv.z, wr1[q*4+2], s1);
        s0 = fmaf(tv.w, wr0[q*4+3], s0); s1 = fmaf(tv.w, wr1[q*4+3], s1);
      }
      acc[QB + k][0] += s0;
      acc[QB + k][1] += s1;
    }
  }
  __syncthreads();
}

template<bool TWOPASS>
__global__ __launch_bounds__(256)
void e3_edge_kernel(TPConsts K,
    const float* __restrict__ f_in, const float* __restrict__ pos,
    const int*   __restrict__ batch,
    const int*   __restrict__ esrc, const int* __restrict__ edst,
    const float* __restrict__ eshift, const float* __restrict__ cell,
    const float* __restrict__ w0, const float* __restrict__ b0,
    const float* __restrict__ w1, const float* __restrict__ b1,
    const float* __restrict__ w2, const float* __restrict__ b2,
    const float* __restrict__ w3, const float* __restrict__ b3,
    float* __restrict__ msg_or_out)
{
  __shared__ float S[S_TOT];
  int* s_src = (int*)(S + O_SD);
  int* s_dst = s_src + 32;
  const int t = threadIdx.x;
  const int e0 = blockIdx.x * EB;

  // ---- geometry / SH / radial ----
  if (t < EB){
    const int eg  = e0 + t;
    const int src = esrc[eg];
    const int dst = edst[eg];
    s_src[t] = src; s_dst[t] = dst;
    const int g = batch[src];
    const float sx = eshift[eg*3+0], sy = eshift[eg*3+1], sz = eshift[eg*3+2];
    const float* cg = cell + g*9;
    float vx = pos[dst*3+0] - pos[src*3+0] + sx*cg[0] + sy*cg[3] + sz*cg[6];
    float vy = pos[dst*3+1] - pos[src*3+1] + sx*cg[1] + sy*cg[4] + sz*cg[7];
    float vz = pos[dst*3+2] - pos[src*3+2] + sx*cg[2] + sy*cg[5] + sz*cg[8];
    float r  = sqrtf(vx*vx + vy*vy + vz*vz + 1e-12f);
    float inv = 1.0f / r;
    float x = vx*inv, y = vy*inv, z = vz*inv;
    const float s3 = 1.7320508075688772f, s5 = 2.23606797749979f, s15 = 3.872983346207417f;
    S[O_SH + t*12 + 0] = 1.0f;
    S[O_SH + t*12 + 1] = s3 * y;
    S[O_SH + t*12 + 2] = s3 * z;
    S[O_SH + t*12 + 3] = s3 * x;
    S[O_SH + t*12 + 4] = s15 * x * y;
    S[O_SH + t*12 + 5] = s15 * y * z;
    S[O_SH + t*12 + 6] = 0.5f * s5 * (3.0f*z*z - 1.0f);
    S[O_SH + t*12 + 7] = s15 * x * z;
    S[O_SH + t*12 + 8] = 0.5f * s15 * (x*x - y*y);
    float xr   = fminf(fmaxf(r * (1.0f/6.0f), 0.0f), 1.0f);
    float mask = (r <= 6.0f) ? 2.8284271247461903f : 0.0f;
    #pragma unroll
    for (int b = 0; b < 8; ++b){
      float d = (xr - (float)b * (1.0f/7.0f)) * 7.0f;
      S[O_EMB + t*8 + b] = mask * expf(-0.5f * d * d);
    }
  }
  __syncthreads();

  // ---- gather f_in rows (float4) ----
  for (int i = t; i < EB*36; i += 256){
    const int e = i / 36, c4 = i - e*36;
    *(float4*)(S + O_X1 + e*144 + c4*4) =
        *(const float4*)(f_in + (size_t)s_src[e]*144 + c4*4);
  }

  // ---- MLP layer 0 (8 -> 64) ----
  #pragma unroll
  for (int it = 0; it < 8; ++it){
    const int idx = t + it*256;
    const int e = idx & 31, o = idx >> 5;
    float s = b0[o];
    #pragma unroll
    for (int c = 0; c < 8; ++c) s = fmaf(S[O_EMB + e*8 + c], w0[c*64 + o], s);
    S[O_HA + e*65 + o] = silu_f(s);
  }
  __syncthreads();
  // ---- layer 1 ----
  #pragma unroll
  for (int it = 0; it < 8; ++it){
    const int idx = t + it*256;
    const int e = idx & 31, o = idx >> 5;
    float s = b1[o];
    for (int c = 0; c < 64; ++c) s = fmaf(S[O_HA + e*65 + c], w1[c*64 + o], s);
    S[O_HB + e*65 + o] = silu_f(s);
  }
  __syncthreads();
  // ---- layer 2 -> transposed hT[c][e] ----
  #pragma unroll
  for (int it = 0; it < 8; ++it){
    const int idx = t + it*256;
    const int e = idx & 31, o = idx >> 5;
    float s = b2[o];
    for (int c = 0; c < 64; ++c) s = fmaf(S[O_HB + e*65 + c], w2[c*64 + o], s);
    S[O_HT + o*32 + e] = silu_f(s);
  }
  __syncthreads();

  // ---- 11 paths ----
  float acc[9][2];
  #pragma unroll
  for (int q = 0; q < 9; ++q){ acc[q][0] = 0.0f; acc[q][1] = 0.0f; }

  //        <P, D1,D2,D3, QB, COFF, XOFF, SHO>
  path_step<0, 1,1,1, 0,   0,  0, 0>(K, S, w3, b3, acc);
  path_step<4, 3,3,1, 0,  44, 16, 1>(K, S, w3, b3, acc);
  path_step<9, 5,5,1, 0, 213, 64, 4>(K, S, w3, b3, acc);
  path_step<1, 1,3,3, 1,   1,  0, 1>(K, S, w3, b3, acc);
  path_step<3, 3,1,3, 1,  35, 16, 0>(K, S, w3, b3, acc);
  path_step<6, 3,5,3, 1,  98, 16, 4>(K, S, w3, b3, acc);
  path_step<8, 5,3,3, 1, 168, 64, 1>(K, S, w3, b3, acc);
  path_step<2, 1,5,5, 4,  10,  0, 4>(K, S, w3, b3, acc);
  path_step<5, 3,3,5, 4,  53, 16, 1>(K, S, w3, b3, acc);
  path_step<7, 5,1,5, 4, 143, 64, 0>(K, S, w3, b3, acc);
  path_step<10,5,5,5, 4, 238, 64, 4>(K, S, w3, b3, acc);

  // ---- emit ----
  const int e_c = t >> 3;
  const int w2i = t & 7;
  if (TWOPASS){
    // stage to LDS (reuse W region) then coalesced float4 store to msg buffer
    #pragma unroll
    for (int q = 0; q < 9; ++q){
      S[O_W + e_c*144 + q*16 + w2i    ] = acc[q][0];
      S[O_W + e_c*144 + q*16 + w2i + 8] = acc[q][1];
    }
    __syncthreads();
    for (int i = t; i < EB*36; i += 256){
      const int e = i / 36, c4 = i - e*36;
      *(float4*)(msg_or_out + (size_t)(e0 + e)*144 + c4*4) =
          *(const float4*)(S + O_W + e*144 + c4*4);
    }
  } else {
    float* op = msg_or_out + (size_t)s_dst[e_c]*144 + w2i;
    #pragma unroll
    for (int q = 0; q < 9; ++q){
      atomicAdd(op + q*16,     acc[q][0]);
      atomicAdd(op + q*16 + 8, acc[q][1]);
    }
  }
}

// ---------------- scatter infrastructure ----------------
__global__ __launch_bounds__(256)
void e3_hist(const int* __restrict__ edst, int* __restrict__ cnt){
  int e = blockIdx.x*256 + threadIdx.x;
  if (e < NEDGES) atomicAdd(&cnt[edst[e]], 1);
}

__global__ __launch_bounds__(1024)
void e3_scan(const int* __restrict__ cnt, int* __restrict__ offs, int* __restrict__ cursor, int n){
  __shared__ int buf[1024];
  __shared__ int carry;
  const int t = threadIdx.x;
  if (t == 0) carry = 0;
  __syncthreads();
  for (int base = 0; base < n; base += 1024){
    int v = (base + t < n) ? cnt[base + t] : 0;
    buf[t] = v;
    __syncthreads();
    for (int d = 1; d < 1024; d <<= 1){
      int x = (t >= d) ? buf[t - d] : 0;
      __syncthreads();
      buf[t] += x;
      __syncthreads();
    }
    const int base_c = carry;
    if (base + t < n){
      const int ex = base_c + buf[t] - v;
      offs[base + t]   = ex;
      cursor[base + t] = ex;
    }
    __syncthreads();
    if (t == 1023) carry = base_c + buf[1023];
    __syncthreads();
  }
  if (t == 0) offs[n] = carry;
}

__global__ __launch_bounds__(256)
void e3_fill(const int* __restrict__ edst, int* __restrict__ cursor, int* __restrict__ eidx){
  int e = blockIdx.x*256 + threadIdx.x;
  if (e < NEDGES){
    int pos = atomicAdd(&cursor[edst[e]], 1);
    eidx[pos] = e;
  }
}

__global__ __launch_bounds__(192)
void e3_reduce(const float* __restrict__ msg, const int* __restrict__ offs,
               const int* __restrict__ eidx, float* __restrict__ out){
  const int nid = blockIdx.x;
  const int t = threadIdx.x;
  if (t >= 144) return;
  const int beg = offs[nid], end = offs[nid + 1];
  float a0 = 0.f, a1 = 0.f, a2 = 0.f, a3 = 0.f;
  int i = beg;
  for (; i + 4 <= end; i += 4){
    const int i0 = eidx[i], i1 = eidx[i+1], i2 = eidx[i+2], i3 = eidx[i+3];
    a0 += msg[(size_t)i0*144 + t];
    a1 += msg[(size_t)i1*144 + t];
    a2 += msg[(size_t)i2*144 + t];
    a3 += msg[(size_t)i3*144 + t];
  }
  for (; i < end; ++i) a0 += msg[(size_t)eidx[i]*144 + t];
  const float deg = (float)(end - beg);
  out[(size_t)nid*144 + t] = (a0 + a1 + a2 + a3) / fmaxf(deg, 1.0f);
}

__global__ __launch_bounds__(256)
void e3_div(float* __restrict__ out, const int* __restrict__ cnt, int n){
  int i = blockIdx.x*256 + threadIdx.x;
  if (i < n){
    float c = (float)cnt[i / INDIM];
    out[i] /= fmaxf(c, 1.0f);
  }
}

extern "C" void kernel_launch(void* const* d_in, const int* in_sizes, int n_in,
                              void* d_out, int out_size, void* d_ws, size_t ws_size,
                              hipStream_t stream)
{
  const float* f_in   = (const float*)d_in[0];
  const float* pos    = (const float*)d_in[1];
  const int*   batch  = (const int*)  d_in[3];
  const int*   esrc   = (const int*)  d_in[4];
  const int*   edst   = (const int*)  d_in[5];
  const float* eshift = (const float*)d_in[6];
  const float* cell   = (const float*)d_in[7];
  const float* w0 = (const float*)d_in[8];  const float* b0 = (const float*)d_in[9];
  const float* w1 = (const float*)d_in[10]; const float* b1 = (const float*)d_in[11];
  const float* w2 = (const float*)d_in[12]; const float* b2 = (const float*)d_in[13];
  const float* w3 = (const float*)d_in[14]; const float* b3 = (const float*)d_in[15];
  float* out = (float*)d_out;

  // workspace layout (ints): cnt[10240] @0; offs[10241] @16384; cursor @32768;
  // eidx[160000] @49152; msg floats @ byte offset 1 MiB
  int* cnt_i  = (int*)d_ws;
  int* offs   = (int*)d_ws + 16384;
  int* cursor = (int*)d_ws + 32768;
  int* eidx   = (int*)d_ws + 49152;
  float* msg  = (float*)((char*)d_ws + (1u << 20));
  const size_t need = (1u << 20) + (size_t)NEDGES * INDIM * sizeof(float);
  const bool twopass = ws_size >= need;

  TPConsts K = build_consts();

  hipMemsetAsync(cnt_i, 0, 10240 * sizeof(int), stream);
  e3_hist<<<(NEDGES + 255)/256, 256, 0, stream>>>(edst, cnt_i);

  if (twopass){
    e3_scan<<<1, 1024, 0, stream>>>(cnt_i, offs, cursor, NNODES);
    e3_fill<<<(NEDGES + 255)/256, 256, 0, stream>>>(edst, cursor, eidx);
    e3_edge_kernel<true><<<NEDGES/EB, 256, 0, stream>>>(K,
        f_in, pos, batch, esrc, edst, eshift, cell,
        w0, b0, w1, b1, w2, b2, w3, b3, msg);
    e3_reduce<<<NNODES, 192, 0, stream>>>(msg, offs, eidx, out);
  } else {
    hipMemsetAsync(d_out, 0, (size_t)out_size * sizeof(float), stream);
    e3_edge_kernel<false><<<NEDGES/EB, 256, 0, stream>>>(K,
        f_in, pos, batch, esrc, edst, eshift, cell,
        w0, b0, w1, b1, w2, b2, w3, b3, out);
    e3_div<<<(out_size + 255)/256, 256, 0, stream>>>(out, cnt_i, out_size);
  }
}

// Round 3
// 647.721 us; speedup vs baseline: 59.5284x; 3.1894x over previous
//
#include <hip/hip_runtime.h>
#include <cmath>
#include <complex>
#include <algorithm>

#define NPATH   11
#define NNODES  10000
#define NEDGES  160000
#define EB      64
#define INDIM   144

struct TPConsts { float coef[363]; };

// ---------------- host: exact port of reference Wigner-3j construction ----------------
static double factd(int n){ double r = 1.0; for (int i = 2; i <= n; ++i) r *= (double)i; return r; }

static double su2_cg(int j1,int m1,int j2,int m2,int j3,int m3){
  if (m3 != m1 + m2) return 0.0;
  int vmin = std::max(std::max(-j1 + j2 + m3, -j1 + m1), 0);
  int vmax = std::min(std::min(j2 + j3 + m1, j3 - j1 + j2), j3 + m3);
  double C = std::sqrt((2.0*j3 + 1.0)
      * factd(j3 + j1 - j2) * factd(j3 - j1 + j2) * factd(j1 + j2 - j3) / factd(j1 + j2 + j3 + 1)
      * factd(j3 + m3) * factd(j3 - m3)
      / (factd(j1 - m1) * factd(j1 + m1) * factd(j2 - m2) * factd(j2 + m2)));
  double S = 0.0;
  for (int v = vmin; v <= vmax; ++v){
    double sgn = ((v + j2 + m2) & 1) ? -1.0 : 1.0;
    S += sgn / factd(v) * factd(j2 + j3 + m1 - v) * factd(j1 - m1 + v)
         / factd(j3 - j1 + j2 - v) / factd(j3 + m3 - v) / factd(v + j1 - j2 - m3);
  }
  return C * S;
}

static void qmat(int l, std::complex<double>* q){
  int n = 2*l + 1;
  for (int i = 0; i < n*n; ++i) q[i] = 0.0;
  const double is2 = 1.0 / std::sqrt(2.0);
  const std::complex<double> I(0.0, 1.0);
  for (int m = -l; m < 0; ++m){
    q[(l+m)*n + (l-m)] = is2;
    q[(l+m)*n + (l+m)] = -I * is2;
  }
  q[l*n + l] = 1.0;
  for (int m = 1; m <= l; ++m){
    double sgn = (m & 1) ? -1.0 : 1.0;
    q[(l+m)*n + (l+m)] = sgn * is2;
    q[(l+m)*n + (l-m)] = I * sgn * is2;
  }
  std::complex<double> ph(1.0, 0.0);
  for (int i = 0; i < l; ++i) ph *= std::complex<double>(0.0, -1.0);
  for (int i = 0; i < n*n; ++i) q[i] *= ph;
}

static void w3j_tensor(int l1,int l2,int l3, double* out){
  int n1 = 2*l1+1, n2 = 2*l2+1, n3 = 2*l3+1;
  std::complex<double> C[125];
  for (int a = 0; a < n1; ++a)
    for (int b = 0; b < n2; ++b)
      for (int c = 0; c < n3; ++c)
        C[(a*n2 + b)*n3 + c] = su2_cg(l1, a - l1, l2, b - l2, l3, c - l3);
  std::complex<double> q1[25], q2[25], q3[25];
  qmat(l1, q1); qmat(l2, q2); qmat(l3, q3);
  double norm = 0.0;
  for (int j = 0; j < n1; ++j)
    for (int lq = 0; lq < n2; ++lq)
      for (int m = 0; m < n3; ++m){
        std::complex<double> s(0.0, 0.0);
        for (int i = 0; i < n1; ++i)
          for (int k = 0; k < n2; ++k)
            for (int nn = 0; nn < n3; ++nn)
              s += q1[i*n1 + j] * q2[k*n2 + lq] * std::conj(q3[nn*n3 + m]) * C[(i*n2 + k)*n3 + nn];
        double v = s.real();
        out[(j*n2 + lq)*n3 + m] = v;
        norm += v * v;
      }
  norm = std::sqrt(norm);
  for (int i = 0; i < n1*n2*n3; ++i) out[i] /= norm;
}

static TPConsts build_consts(){
  TPConsts K;
  const int PL1[NPATH] = {0,0,0,1,1,1,1,2,2,2,2};
  const int PL2[NPATH] = {0,1,2,0,1,1,2,0,1,2,2};
  const int PL3[NPATH] = {0,1,2,1,0,2,1,2,1,0,2};
  const double FAN[3]  = {48.0, 64.0, 64.0};
  double buf[125];
  int off = 0;
  for (int p = 0; p < NPATH; ++p){
    int l1 = PL1[p], l2 = PL2[p], l3 = PL3[p];
    int n = (2*l1+1)*(2*l2+1)*(2*l3+1);
    w3j_tensor(l1, l2, l3, buf);
    double alpha = std::sqrt((double)(2*l3+1)) / std::sqrt(FAN[l3]);
    for (int i = 0; i < n; ++i) K.coef[off + i] = (float)(buf[i] * alpha);
    off += n;
  }
  return K;
}

// ---------------- device helpers ----------------
typedef __attribute__((ext_vector_type(8))) short bf16x8;
typedef __attribute__((ext_vector_type(4))) float f32x4;

__device__ __forceinline__ float silu_f(float v){ return v / (1.0f + expf(-v)); }
__device__ __forceinline__ float b2f(unsigned short u){
  union { unsigned i; float f; } x; x.i = ((unsigned)u) << 16; return x.f;
}
__device__ __forceinline__ unsigned short f2b(float f){
  union { float f; unsigned i; } x; x.f = f;
  unsigned r = x.i + 0x7FFFu + ((x.i >> 16) & 1u);
  return (unsigned short)(r >> 16);
}

// LDS float offsets (total 15040 floats = 60160 B)
#define O_X1  0       // [144][64] f32 x1 transposed; aliased by hA/hB during MLP
#define O_SH  9216    // [9][64]  f32 sh transposed
#define O_TP  9792    // bf16 [5][16][64] = 2560 floats
#define O_HB  12352   // bf16 h [64][64] = 2048 floats
#define O_EMB 14400   // [64][8] f32
#define O_SD  14912   // src[64], dst[64] ints
#define S_TOT 15040

// One path: CG contraction -> barrier -> MFMA W-gen + consume -> barrier.
template<int P,int D1,int D2,int D3,int QB,int COFF,int XOFF,int SHO,bool TWOPASS>
__device__ __forceinline__ void path_step(
    const TPConsts& K, float* S,
    const unsigned short* __restrict__ w3T, const float* __restrict__ b3,
    const bf16x8& ha0, const bf16x8& ha1,
    float (&acc)[9][4])
{
  const int t = threadIdx.x;
  unsigned short* tp16 = (unsigned short*)(S + O_TP);

  // ---- CG: tmp[k][u][e] (bf16), thread = (u = t>>5, edge-pair eg = t&31) ----
  {
    const int eg = t & 31, u = t >> 5;
    float a0[D3], a1[D3];
    #pragma unroll
    for (int k = 0; k < D3; ++k){ a0[k] = 0.0f; a1[k] = 0.0f; }
    #pragma unroll
    for (int i = 0; i < D1; ++i){
      const float2 xv = *(const float2*)(S + O_X1 + (XOFF + i*16 + u)*64 + eg*2);
      #pragma unroll
      for (int j = 0; j < D2; ++j){
        const float2 sv = *(const float2*)(S + O_SH + (SHO + j)*64 + eg*2);
        const float p0 = xv.x * sv.x, p1 = xv.y * sv.y;
        #pragma unroll
        for (int k = 0; k < D3; ++k){
          const float cf = K.coef[COFF + (i*D2 + j)*D3 + k];
          a0[k] = fmaf(cf, p0, a0[k]);
          a1[k] = fmaf(cf, p1, a1[k]);
        }
      }
    }
    #pragma unroll
    for (int k = 0; k < D3; ++k){
      ushort2 v; v.x = f2b(a0[k]); v.y = f2b(a1[k]);
      *(ushort2*)(tp16 + (k*16 + u)*64 + eg*2) = v;
    }
  }
  __syncthreads();

  // ---- MFMA W-gen + consume ----
  {
    const int lane = t & 63, wid = t >> 6;
    const int ch = wid & 1, r0 = (wid >> 1) * 16;
    const int lw = lane & 15, rg = lane >> 4;
    #pragma unroll
    for (int jt = 0; jt < 8; ++jt){
      const int n = P*256 + ch*128 + jt*16 + lw;      // w3 column index
      const bf16x8 b0 = *(const bf16x8*)(w3T + (size_t)n*64 + rg*8);
      const bf16x8 b1 = *(const bf16x8*)(w3T + (size_t)n*64 + 32 + rg*8);
      const float bv = b3[n];
      f32x4 c = {bv, bv, bv, bv};
      c = __builtin_amdgcn_mfma_f32_16x16x32_bf16(ha0, b0, c, 0, 0, 0);
      c = __builtin_amdgcn_mfma_f32_16x16x32_bf16(ha1, b1, c, 0, 0, 0);
      const int j = ch*8 + jt;                        // u index
      #pragma unroll
      for (int k = 0; k < D3; ++k){
        const ushort4 tv = *(const ushort4*)(tp16 + (k*16 + j)*64 + r0 + rg*4);
        acc[QB+k][0] = fmaf(b2f(tv.x), c[0], acc[QB+k][0]);
        acc[QB+k][1] = fmaf(b2f(tv.y), c[1], acc[QB+k][1]);
        acc[QB+k][2] = fmaf(b2f(tv.z), c[2], acc[QB+k][2]);
        acc[QB+k][3] = fmaf(b2f(tv.w), c[3], acc[QB+k][3]);
      }
    }
  }
  __syncthreads();
}

template<bool TWOPASS>
__global__ __launch_bounds__(512, 4)
void e3_fused(TPConsts K,
    const float* __restrict__ f_in, const float* __restrict__ pos,
    const int*   __restrict__ batch,
    const int*   __restrict__ esrc, const int* __restrict__ edst,
    const float* __restrict__ eshift, const float* __restrict__ cell,
    const float* __restrict__ w0, const float* __restrict__ b0,
    const float* __restrict__ w1, const float* __restrict__ b1,
    const float* __restrict__ w2, const float* __restrict__ b2,
    const float* __restrict__ b3, const unsigned short* __restrict__ w3T,
    float* __restrict__ msg_or_out)
{
  __shared__ float S[S_TOT];
  int* s_src = (int*)(S + O_SD);
  int* s_dst = s_src + EB;
  unsigned short* h16 = (unsigned short*)(S + O_HB);
  const int t = threadIdx.x;
  const int e0 = blockIdx.x * EB;

  // ---- geometry / SH / radial (one thread per edge) ----
  if (t < EB){
    const int eg  = e0 + t;
    const int src = esrc[eg];
    const int dst = edst[eg];
    s_src[t] = src; s_dst[t] = dst;
    const int g = batch[src];
    const float sx = eshift[eg*3+0], sy = eshift[eg*3+1], sz = eshift[eg*3+2];
    const float* cg = cell + g*9;
    float vx = pos[dst*3+0] - pos[src*3+0] + sx*cg[0] + sy*cg[3] + sz*cg[6];
    float vy = pos[dst*3+1] - pos[src*3+1] + sx*cg[1] + sy*cg[4] + sz*cg[7];
    float vz = pos[dst*3+2] - pos[src*3+2] + sx*cg[2] + sy*cg[5] + sz*cg[8];
    float r  = sqrtf(vx*vx + vy*vy + vz*vz + 1e-12f);
    float inv = 1.0f / r;
    float x = vx*inv, y = vy*inv, z = vz*inv;
    const float s3 = 1.7320508075688772f, s5 = 2.23606797749979f, s15 = 3.872983346207417f;
    S[O_SH + 0*64 + t] = 1.0f;
    S[O_SH + 1*64 + t] = s3 * y;
    S[O_SH + 2*64 + t] = s3 * z;
    S[O_SH + 3*64 + t] = s3 * x;
    S[O_SH + 4*64 + t] = s15 * x * y;
    S[O_SH + 5*64 + t] = s15 * y * z;
    S[O_SH + 6*64 + t] = 0.5f * s5 * (3.0f*z*z - 1.0f);
    S[O_SH + 7*64 + t] = s15 * x * z;
    S[O_SH + 8*64 + t] = 0.5f * s15 * (x*x - y*y);
    float xr   = fminf(fmaxf(r * (1.0f/6.0f), 0.0f), 1.0f);
    float mask = (r <= 6.0f) ? 2.8284271247461903f : 0.0f;
    #pragma unroll
    for (int b = 0; b < 8; ++b){
      float d = (xr - (float)b * (1.0f/7.0f)) * 7.0f;
      S[O_EMB + t*8 + b] = mask * expf(-0.5f * d * d);
    }
  }
  __syncthreads();

  // ---- MLP (hA/hB alias the x1 region; x1 gathered afterwards) ----
  float* hA = S + O_X1;           // [64][65]
  float* hB = S + O_X1 + 4160;    // [64][65]
  const int o = t & 63, egr = t >> 6;   // 8 edges per thread
  {
    float s[8];
    #pragma unroll
    for (int e8 = 0; e8 < 8; ++e8) s[e8] = b0[o];
    #pragma unroll
    for (int c = 0; c < 8; ++c){
      const float wv = w0[c*64 + o];
      #pragma unroll
      for (int e8 = 0; e8 < 8; ++e8)
        s[e8] = fmaf(S[O_EMB + (egr*8 + e8)*8 + c], wv, s[e8]);
    }
    #pragma unroll
    for (int e8 = 0; e8 < 8; ++e8) hA[(egr*8 + e8)*65 + o] = silu_f(s[e8]);
  }
  __syncthreads();
  {
    float s[8];
    #pragma unroll
    for (int e8 = 0; e8 < 8; ++e8) s[e8] = b1[o];
    for (int c = 0; c < 64; ++c){
      const float wv = w1[c*64 + o];
      #pragma unroll
      for (int e8 = 0; e8 < 8; ++e8)
        s[e8] = fmaf(hA[(egr*8 + e8)*65 + c], wv, s[e8]);
    }
    #pragma unroll
    for (int e8 = 0; e8 < 8; ++e8) hB[(egr*8 + e8)*65 + o] = silu_f(s[e8]);
  }
  __syncthreads();
  {
    float s[8];
    #pragma unroll
    for (int e8 = 0; e8 < 8; ++e8) s[e8] = b2[o];
    for (int c = 0; c < 64; ++c){
      const float wv = w2[c*64 + o];
      #pragma unroll
      for (int e8 = 0; e8 < 8; ++e8)
        s[e8] = fmaf(hB[(egr*8 + e8)*65 + c], wv, s[e8]);
    }
    #pragma unroll
    for (int e8 = 0; e8 < 8; ++e8) h16[(egr*8 + e8)*64 + o] = f2b(silu_f(s[e8]));
  }
  __syncthreads();

  // ---- gather x1 transposed: x1T[c][e] ----
  for (int idx = t; idx < EB*36; idx += 512){
    const int e = idx / 36, c4 = idx - e*36;
    const float4 v = *(const float4*)(f_in + (size_t)s_src[e]*INDIM + c4*4);
    S[O_X1 + (c4*4 + 0)*64 + e] = v.x;
    S[O_X1 + (c4*4 + 1)*64 + e] = v.y;
    S[O_X1 + (c4*4 + 2)*64 + e] = v.z;
    S[O_X1 + (c4*4 + 3)*64 + e] = v.w;
  }

  // ---- A-fragments (h), held across all paths ----
  const int lane = t & 63, wid = t >> 6;
  const int lw = lane & 15, rg = lane >> 4;
  const int r0 = (wid >> 1) * 16;
  const bf16x8 ha0 = *(const bf16x8*)((const char*)h16 + (r0 + lw)*128 + rg*16);
  const bf16x8 ha1 = *(const bf16x8*)((const char*)h16 + (r0 + lw)*128 + 64 + rg*16);
  __syncthreads();

  float acc[9][4];
  #pragma unroll
  for (int q = 0; q < 9; ++q)
    #pragma unroll
    for (int i = 0; i < 4; ++i) acc[q][i] = 0.0f;

  //        <P, D1,D2,D3, QB, COFF, XOFF, SHO, TWOPASS>
  path_step<0, 1,1,1, 0,   0,  0, 0, TWOPASS>(K, S, w3T, b3, ha0, ha1, acc);
  path_step<1, 1,3,3, 1,   1,  0, 1, TWOPASS>(K, S, w3T, b3, ha0, ha1, acc);
  path_step<2, 1,5,5, 4,  10,  0, 4, TWOPASS>(K, S, w3T, b3, ha0, ha1, acc);
  path_step<3, 3,1,3, 1,  35, 16, 0, TWOPASS>(K, S, w3T, b3, ha0, ha1, acc);
  path_step<4, 3,3,1, 0,  44, 16, 1, TWOPASS>(K, S, w3T, b3, ha0, ha1, acc);
  path_step<5, 3,3,5, 4,  53, 16, 1, TWOPASS>(K, S, w3T, b3, ha0, ha1, acc);
  path_step<6, 3,5,3, 1,  98, 16, 4, TWOPASS>(K, S, w3T, b3, ha0, ha1, acc);
  path_step<7, 5,1,5, 4, 143, 64, 0, TWOPASS>(K, S, w3T, b3, ha0, ha1, acc);
  path_step<8, 5,3,3, 1, 168, 64, 1, TWOPASS>(K, S, w3T, b3, ha0, ha1, acc);
  path_step<9, 5,5,1, 0, 213, 64, 4, TWOPASS>(K, S, w3T, b3, ha0, ha1, acc);
  path_step<10,5,5,5, 4, 238, 64, 4, TWOPASS>(K, S, w3T, b3, ha0, ha1, acc);

  // ---- emit: combine the two col-half waves, then write ----
  const int ch = wid & 1;
  if (TWOPASS){
    // stage into x1 region [e][144]
    if (ch == 0){
      #pragma unroll
      for (int q = 0; q < 9; ++q)
        #pragma unroll
        for (int i = 0; i < 4; ++i)
          S[O_X1 + (r0 + rg*4 + i)*INDIM + q*16 + lw] = acc[q][i];
    }
    __syncthreads();
    if (ch == 1){
      #pragma unroll
      for (int q = 0; q < 9; ++q)
        #pragma unroll
        for (int i = 0; i < 4; ++i)
          S[O_X1 + (r0 + rg*4 + i)*INDIM + q*16 + lw] += acc[q][i];
    }
    __syncthreads();
    for (int idx = t; idx < EB*36; idx += 512){
      const int e = idx / 36, c4 = idx - e*36;
      *(float4*)(msg_or_out + (size_t)(e0 + e)*INDIM + c4*4) =
          *(const float4*)(S + O_X1 + e*INDIM + c4*4);
    }
  } else {
    #pragma unroll
    for (int i = 0; i < 4; ++i){
      const int e = r0 + rg*4 + i;
      float* op = msg_or_out + (size_t)s_dst[e]*INDIM + lw;
      #pragma unroll
      for (int q = 0; q < 9; ++q) atomicAdd(op + q*16, acc[q][i]);
    }
  }
}

// ---------------- w3 -> bf16 transposed [n][k] ----------------
__global__ __launch_bounds__(256)
void w3_cvt(const float* __restrict__ w3, unsigned short* __restrict__ w3T){
  const int id = blockIdx.x*256 + threadIdx.x;
  if (id < 64*2816){
    const int n = id >> 6, k = id & 63;
    w3T[id] = f2b(w3[(size_t)k*2816 + n]);
  }
}

// ---------------- scatter infrastructure ----------------
__global__ __launch_bounds__(256)
void e3_hist(const int* __restrict__ edst, int* __restrict__ cnt){
  int e = blockIdx.x*256 + threadIdx.x;
  if (e < NEDGES) atomicAdd(&cnt[edst[e]], 1);
}

__global__ __launch_bounds__(1024)
void e3_scan(const int* __restrict__ cnt, int* __restrict__ offs, int* __restrict__ cursor, int n){
  __shared__ int buf[1024];
  __shared__ int carry;
  const int t = threadIdx.x;
  if (t == 0) carry = 0;
  __syncthreads();
  for (int base = 0; base < n; base += 1024){
    int v = (base + t < n) ? cnt[base + t] : 0;
    buf[t] = v;
    __syncthreads();
    for (int d = 1; d < 1024; d <<= 1){
      int x = (t >= d) ? buf[t - d] : 0;
      __syncthreads();
      buf[t] += x;
      __syncthreads();
    }
    const int base_c = carry;
    if (base + t < n){
      const int ex = base_c + buf[t] - v;
      offs[base + t]   = ex;
      cursor[base + t] = ex;
    }
    __syncthreads();
    if (t == 1023) carry = base_c + buf[1023];
    __syncthreads();
  }
  if (t == 0) offs[n] = carry;
}

__global__ __launch_bounds__(256)
void e3_fill(const int* __restrict__ edst, int* __restrict__ cursor, int* __restrict__ eidx){
  int e = blockIdx.x*256 + threadIdx.x;
  if (e < NEDGES){
    int pos = atomicAdd(&cursor[edst[e]], 1);
    eidx[pos] = e;
  }
}

__global__ __launch_bounds__(192)
void e3_reduce(const float* __restrict__ msg, const int* __restrict__ offs,
               const int* __restrict__ eidx, float* __restrict__ out){
  const int nid = blockIdx.x;
  const int t = threadIdx.x;
  if (t >= 144) return;
  const int beg = offs[nid], end = offs[nid + 1];
  float a0 = 0.f, a1 = 0.f, a2 = 0.f, a3 = 0.f;
  int i = beg;
  for (; i + 4 <= end; i += 4){
    const int i0 = eidx[i], i1 = eidx[i+1], i2 = eidx[i+2], i3 = eidx[i+3];
    a0 += msg[(size_t)i0*INDIM + t];
    a1 += msg[(size_t)i1*INDIM + t];
    a2 += msg[(size_t)i2*INDIM + t];
    a3 += msg[(size_t)i3*INDIM + t];
  }
  for (; i < end; ++i) a0 += msg[(size_t)eidx[i]*INDIM + t];
  const float deg = (float)(end - beg);
  out[(size_t)nid*INDIM + t] = (a0 + a1 + a2 + a3) / fmaxf(deg, 1.0f);
}

__global__ __launch_bounds__(256)
void e3_div(float* __restrict__ out, const int* __restrict__ cnt, int n){
  int i = blockIdx.x*256 + threadIdx.x;
  if (i < n){
    float c = (float)cnt[i / INDIM];
    out[i] /= fmaxf(c, 1.0f);
  }
}

extern "C" void kernel_launch(void* const* d_in, const int* in_sizes, int n_in,
                              void* d_out, int out_size, void* d_ws, size_t ws_size,
                              hipStream_t stream)
{
  const float* f_in   = (const float*)d_in[0];
  const float* pos    = (const float*)d_in[1];
  const int*   batch  = (const int*)  d_in[3];
  const int*   esrc   = (const int*)  d_in[4];
  const int*   edst   = (const int*)  d_in[5];
  const float* eshift = (const float*)d_in[6];
  const float* cell   = (const float*)d_in[7];
  const float* w0 = (const float*)d_in[8];  const float* b0 = (const float*)d_in[9];
  const float* w1 = (const float*)d_in[10]; const float* b1 = (const float*)d_in[11];
  const float* w2 = (const float*)d_in[12]; const float* b2 = (const float*)d_in[13];
  const float* w3 = (const float*)d_in[14]; const float* b3 = (const float*)d_in[15];
  float* out = (float*)d_out;

  // twopass ws layout (ints): cnt[10240]@0; offs@16384; cursor@32768; eidx@49152;
  // msg floats @ 1 MiB.  w3T (bf16, 360448 B) lives in d_out until e3_reduce overwrites it.
  const size_t need = (1u << 20) + (size_t)NEDGES * INDIM * sizeof(float);
  const bool twopass = ws_size >= need;

  TPConsts K = build_consts();

  if (twopass){
    int* cnt_i  = (int*)d_ws;
    int* offs   = (int*)d_ws + 16384;
    int* cursor = (int*)d_ws + 32768;
    int* eidx   = (int*)d_ws + 49152;
    float* msg  = (float*)((char*)d_ws + (1u << 20));
    unsigned short* w3T = (unsigned short*)d_out;

    w3_cvt<<<704, 256, 0, stream>>>(w3, w3T);
    hipMemsetAsync(cnt_i, 0, 10240 * sizeof(int), stream);
    e3_hist<<<(NEDGES + 255)/256, 256, 0, stream>>>(edst, cnt_i);
    e3_scan<<<1, 1024, 0, stream>>>(cnt_i, offs, cursor, NNODES);
    e3_fill<<<(NEDGES + 255)/256, 256, 0, stream>>>(edst, cursor, eidx);
    e3_fused<true><<<NEDGES/EB, 512, 0, stream>>>(K,
        f_in, pos, batch, esrc, edst, eshift, cell,
        w0, b0, w1, b1, w2, b2, b3, w3T, msg);
    e3_reduce<<<NNODES, 192, 0, stream>>>(msg, offs, eidx, out);
  } else {
    // fallback: w3T + cnt in ws (needs ~410 KB), atomic scatter
    unsigned short* w3T = (unsigned short*)d_ws;
    int* cnt_i = (int*)((char*)d_ws + 368640);

    w3_cvt<<<704, 256, 0, stream>>>(w3, w3T);
    hipMemsetAsync(cnt_i, 0, NNODES * sizeof(int), stream);
    e3_hist<<<(NEDGES + 255)/256, 256, 0, stream>>>(edst, cnt_i);
    hipMemsetAsync(d_out, 0, (size_t)out_size * sizeof(float), stream);
    e3_fused<false><<<NEDGES/EB, 512, 0, stream>>>(K,
        f_in, pos, batch, esrc, edst, eshift, cell,
        w0, b0, w1, b1, w2, b2, b3, w3T, out);
    e3_div<<<(out_size + 255)/256, 256, 0, stream>>>(out, cnt_i, out_size);
  }
}

// Round 4
// 541.196 us; speedup vs baseline: 71.2455x; 1.1968x over previous
//
#include <hip/hip_runtime.h>
#include <cmath>
#include <complex>
#include <algorithm>

#define NPATH   11
#define NNODES  10000
#define NEDGES  160000
#define EB      64
#define INDIM   144

struct TPConsts { float coef[363]; };

// ---------------- host: exact port of reference Wigner-3j construction ----------------
static double factd(int n){ double r = 1.0; for (int i = 2; i <= n; ++i) r *= (double)i; return r; }

static double su2_cg(int j1,int m1,int j2,int m2,int j3,int m3){
  if (m3 != m1 + m2) return 0.0;
  int vmin = std::max(std::max(-j1 + j2 + m3, -j1 + m1), 0);
  int vmax = std::min(std::min(j2 + j3 + m1, j3 - j1 + j2), j3 + m3);
  double C = std::sqrt((2.0*j3 + 1.0)
      * factd(j3 + j1 - j2) * factd(j3 - j1 + j2) * factd(j1 + j2 - j3) / factd(j1 + j2 + j3 + 1)
      * factd(j3 + m3) * factd(j3 - m3)
      / (factd(j1 - m1) * factd(j1 + m1) * factd(j2 - m2) * factd(j2 + m2)));
  double S = 0.0;
  for (int v = vmin; v <= vmax; ++v){
    double sgn = ((v + j2 + m2) & 1) ? -1.0 : 1.0;
    S += sgn / factd(v) * factd(j2 + j3 + m1 - v) * factd(j1 - m1 + v)
         / factd(j3 - j1 + j2 - v) / factd(j3 + m3 - v) / factd(v + j1 - j2 - m3);
  }
  return C * S;
}

static void qmat(int l, std::complex<double>* q){
  int n = 2*l + 1;
  for (int i = 0; i < n*n; ++i) q[i] = 0.0;
  const double is2 = 1.0 / std::sqrt(2.0);
  const std::complex<double> I(0.0, 1.0);
  for (int m = -l; m < 0; ++m){
    q[(l+m)*n + (l-m)] = is2;
    q[(l+m)*n + (l+m)] = -I * is2;
  }
  q[l*n + l] = 1.0;
  for (int m = 1; m <= l; ++m){
    double sgn = (m & 1) ? -1.0 : 1.0;
    q[(l+m)*n + (l+m)] = sgn * is2;
    q[(l+m)*n + (l-m)] = I * sgn * is2;
  }
  std::complex<double> ph(1.0, 0.0);
  for (int i = 0; i < l; ++i) ph *= std::complex<double>(0.0, -1.0);
  for (int i = 0; i < n*n; ++i) q[i] *= ph;
}

static void w3j_tensor(int l1,int l2,int l3, double* out){
  int n1 = 2*l1+1, n2 = 2*l2+1, n3 = 2*l3+1;
  std::complex<double> C[125];
  for (int a = 0; a < n1; ++a)
    for (int b = 0; b < n2; ++b)
      for (int c = 0; c < n3; ++c)
        C[(a*n2 + b)*n3 + c] = su2_cg(l1, a - l1, l2, b - l2, l3, c - l3);
  std::complex<double> q1[25], q2[25], q3[25];
  qmat(l1, q1); qmat(l2, q2); qmat(l3, q3);
  double norm = 0.0;
  for (int j = 0; j < n1; ++j)
    for (int lq = 0; lq < n2; ++lq)
      for (int m = 0; m < n3; ++m){
        std::complex<double> s(0.0, 0.0);
        for (int i = 0; i < n1; ++i)
          for (int k = 0; k < n2; ++k)
            for (int nn = 0; nn < n3; ++nn)
              s += q1[i*n1 + j] * q2[k*n2 + lq] * std::conj(q3[nn*n3 + m]) * C[(i*n2 + k)*n3 + nn];
        double v = s.real();
        out[(j*n2 + lq)*n3 + m] = v;
        norm += v * v;
      }
  norm = std::sqrt(norm);
  for (int i = 0; i < n1*n2*n3; ++i) out[i] /= norm;
}

static TPConsts build_consts(){
  TPConsts K;
  const int PL1[NPATH] = {0,0,0,1,1,1,1,2,2,2,2};
  const int PL2[NPATH] = {0,1,2,0,1,1,2,0,1,2,2};
  const int PL3[NPATH] = {0,1,2,1,0,2,1,2,1,0,2};
  const double FAN[3]  = {48.0, 64.0, 64.0};
  double buf[125];
  int off = 0;
  for (int p = 0; p < NPATH; ++p){
    int l1 = PL1[p], l2 = PL2[p], l3 = PL3[p];
    int n = (2*l1+1)*(2*l2+1)*(2*l3+1);
    w3j_tensor(l1, l2, l3, buf);
    double alpha = std::sqrt((double)(2*l3+1)) / std::sqrt(FAN[l3]);
    for (int i = 0; i < n; ++i) K.coef[off + i] = (float)(buf[i] * alpha);
    off += n;
  }
  return K;
}

// ---------------- device helpers ----------------
typedef __attribute__((ext_vector_type(8))) short bf16x8;
typedef __attribute__((ext_vector_type(4))) float f32x4;

__device__ __forceinline__ float silu_f(float v){ return v / (1.0f + expf(-v)); }
__device__ __forceinline__ float b2f(unsigned short u){
  union { unsigned i; float f; } x; x.i = ((unsigned)u) << 16; return x.f;
}
__device__ __forceinline__ unsigned short f2b(float f){
  union { float f; unsigned i; } x; x.f = f;
  unsigned r = x.i + 0x7FFFu + ((x.i >> 16) & 1u);
  return (unsigned short)(r >> 16);
}

// ---- LDS layout ----
// bytes: x1 bf16 [144][66] = 19008 | sh f32 [9][64] = 2304 | tmp f32 [80][64] = 20480
//        (emb f32 [8][64] and emit staging alias tmp) | h bf16 [64][72] = 9216 | src/dst = 512
// total 51520 B -> 3 blocks/CU
#define O_SH   4752      // float idx
#define O_TP   5328      // float idx (tmp / emb / emit staging)
#define O_SD   12752     // float idx (src[64], dst[64] ints)
#define S_TOT  12880     // floats
#define H_OFF  20896     // short idx of h [64][72]
#define HPAD   72

__device__ __forceinline__ bf16x8 load_h_frag(const unsigned short* h16, int row, int kbase, int rg){
  return *(const bf16x8*)(h16 + row*HPAD + kbase + rg*8);   // byte addr = row*144 + ... (16B aligned)
}

// One path: CG contraction (f32 tmp) -> barrier -> MFMA W-gen + consume -> barrier.
template<int P,int D1,int D2,int D3,int QB,int COFF,int XOFF,int SHO>
__device__ __forceinline__ void path_step(
    const TPConsts& K, float* S, const unsigned short* x16,
    const unsigned short* __restrict__ w3T, const float* __restrict__ b3,
    const bf16x8& ha0, const bf16x8& ha1,
    float (&acc)[9][4])
{
  const int t = threadIdx.x;

  // ---- CG: tmp[k][u][e] f32; thread = (u = t>>5, edge-pair eg = t&31) ----
  {
    const int eg = t & 31, u = t >> 5;
    float a0[D3], a1[D3];
    #pragma unroll
    for (int k = 0; k < D3; ++k){ a0[k] = 0.0f; a1[k] = 0.0f; }
    #pragma unroll
    for (int i = 0; i < D1; ++i){
      const ushort2 xv2 = *(const ushort2*)(x16 + (XOFF + i*16 + u)*66 + eg*2);
      const float xv0 = b2f(xv2.x), xv1 = b2f(xv2.y);
      #pragma unroll
      for (int j = 0; j < D2; ++j){
        const float2 sv = *(const float2*)(S + O_SH + (SHO + j)*64 + eg*2);
        const float p0 = xv0 * sv.x, p1 = xv1 * sv.y;
        #pragma unroll
        for (int k = 0; k < D3; ++k){
          const float cf = K.coef[COFF + (i*D2 + j)*D3 + k];
          a0[k] = fmaf(cf, p0, a0[k]);
          a1[k] = fmaf(cf, p1, a1[k]);
        }
      }
    }
    #pragma unroll
    for (int k = 0; k < D3; ++k){
      float2 v; v.x = a0[k]; v.y = a1[k];
      *(float2*)(S + O_TP + (k*16 + u)*64 + eg*2) = v;
    }
  }
  __syncthreads();

  // ---- MFMA W-gen + consume ----
  {
    const int lane = t & 63, wid = t >> 6;
    const int ch = wid & 1, r0 = (wid >> 1) * 16;
    const int lw = lane & 15, rg = lane >> 4;
    #pragma unroll
    for (int jt = 0; jt < 8; ++jt){
      const int n = P*256 + ch*128 + jt*16 + lw;      // w3 column index
      const bf16x8 b0 = *(const bf16x8*)(w3T + (size_t)n*64 + rg*8);
      const bf16x8 b1 = *(const bf16x8*)(w3T + (size_t)n*64 + 32 + rg*8);
      const float bv = b3[n];
      f32x4 c = {bv, bv, bv, bv};
      c = __builtin_amdgcn_mfma_f32_16x16x32_bf16(ha0, b0, c, 0, 0, 0);
      c = __builtin_amdgcn_mfma_f32_16x16x32_bf16(ha1, b1, c, 0, 0, 0);
      const int j = ch*8 + jt;                        // u index
      #pragma unroll
      for (int k = 0; k < D3; ++k){
        const f32x4 tv = *(const f32x4*)(S + O_TP + (k*16 + j)*64 + r0 + rg*4);
        acc[QB+k][0] = fmaf(tv[0], c[0], acc[QB+k][0]);
        acc[QB+k][1] = fmaf(tv[1], c[1], acc[QB+k][1]);
        acc[QB+k][2] = fmaf(tv[2], c[2], acc[QB+k][2]);
        acc[QB+k][3] = fmaf(tv[3], c[3], acc[QB+k][3]);
      }
    }
  }
  __syncthreads();
}

template<bool TWOPASS>
__global__ __launch_bounds__(512, 4)
void e3_fused(TPConsts K,
    const float* __restrict__ f_in, const float* __restrict__ pos,
    const int*   __restrict__ batch,
    const int*   __restrict__ esrc, const int* __restrict__ edst,
    const float* __restrict__ eshift, const float* __restrict__ cell,
    const float* __restrict__ w0, const float* __restrict__ b0,
    const float* __restrict__ b1, const float* __restrict__ b2,
    const float* __restrict__ b3, const unsigned short* __restrict__ wT,
    float* __restrict__ msg_or_out)
{
  __shared__ float S[S_TOT];
  unsigned short* x16 = (unsigned short*)S;           // x1 bf16 [144][66]
  unsigned short* h16 = (unsigned short*)S + H_OFF;   // h bf16 [64][72]
  int* s_src = (int*)(S + O_SD);
  int* s_dst = s_src + EB;
  const int t = threadIdx.x;
  const int e0 = blockIdx.x * EB;
  const unsigned short* w3T = wT;
  const unsigned short* w1T = wT + 180224;
  const unsigned short* w2T = wT + 184320;

  // ---- geometry / SH / radial (one thread per edge); emb f32 [8][64] in tmp region ----
  if (t < EB){
    const int eg  = e0 + t;
    const int src = esrc[eg];
    const int dst = edst[eg];
    s_src[t] = src; s_dst[t] = dst;
    const int g = batch[src];
    const float sx = eshift[eg*3+0], sy = eshift[eg*3+1], sz = eshift[eg*3+2];
    const float* cg = cell + g*9;
    float vx = pos[dst*3+0] - pos[src*3+0] + sx*cg[0] + sy*cg[3] + sz*cg[6];
    float vy = pos[dst*3+1] - pos[src*3+1] + sx*cg[1] + sy*cg[4] + sz*cg[7];
    float vz = pos[dst*3+2] - pos[src*3+2] + sx*cg[2] + sy*cg[5] + sz*cg[8];
    float r  = sqrtf(vx*vx + vy*vy + vz*vz + 1e-12f);
    float inv = 1.0f / r;
    float x = vx*inv, y = vy*inv, z = vz*inv;
    const float s3 = 1.7320508075688772f, s5 = 2.23606797749979f, s15 = 3.872983346207417f;
    S[O_SH + 0*64 + t] = 1.0f;
    S[O_SH + 1*64 + t] = s3 * y;
    S[O_SH + 2*64 + t] = s3 * z;
    S[O_SH + 3*64 + t] = s3 * x;
    S[O_SH + 4*64 + t] = s15 * x * y;
    S[O_SH + 5*64 + t] = s15 * y * z;
    S[O_SH + 6*64 + t] = 0.5f * s5 * (3.0f*z*z - 1.0f);
    S[O_SH + 7*64 + t] = s15 * x * z;
    S[O_SH + 8*64 + t] = 0.5f * s15 * (x*x - y*y);
    float xr   = fminf(fmaxf(r * (1.0f/6.0f), 0.0f), 1.0f);
    float mask = (r <= 6.0f) ? 2.8284271247461903f : 0.0f;
    #pragma unroll
    for (int b = 0; b < 8; ++b){
      float d = (xr - (float)b * (1.0f/7.0f)) * 7.0f;
      S[O_TP + b*64 + t] = mask * expf(-0.5f * d * d);
    }
  }
  __syncthreads();

  // ---- gather x1 -> bf16 transposed [c][e], pad 66 (issue early to hide latency) ----
  for (int idx = t; idx < EB*36; idx += 512){
    const int e = idx / 36, c4 = idx - e*36;
    const float4 v = *(const float4*)(f_in + (size_t)s_src[e]*INDIM + c4*4);
    x16[(c4*4 + 0)*66 + e] = f2b(v.x);
    x16[(c4*4 + 1)*66 + e] = f2b(v.y);
    x16[(c4*4 + 2)*66 + e] = f2b(v.z);
    x16[(c4*4 + 3)*66 + e] = f2b(v.w);
  }

  const int lane = t & 63, wid = t >> 6;
  const int lw = lane & 15, rg = lane >> 4;

  // ---- MLP layer 0 (8 -> 64), VALU f32; output bf16 to h ----
  {
    const int o = t & 63, egr = t >> 6;
    float s[8];
    #pragma unroll
    for (int e8 = 0; e8 < 8; ++e8) s[e8] = b0[o];
    #pragma unroll
    for (int c = 0; c < 8; ++c){
      const float wv = w0[c*64 + o];
      #pragma unroll
      for (int e8 = 0; e8 < 8; ++e8)
        s[e8] = fmaf(S[O_TP + c*64 + egr*8 + e8], wv, s[e8]);
    }
    #pragma unroll
    for (int e8 = 0; e8 < 8; ++e8) h16[(egr*8 + e8)*HPAD + o] = f2b(silu_f(s[e8]));
  }
  __syncthreads();

  // ---- MLP layers 1,2 via MFMA: C[e,o] = h @ wT, 16 tiles over 8 waves ----
  const int tr = wid >> 1;            // edge-row tile 0..3
  const int tc0 = (wid & 1) * 2;      // col tiles tc0, tc0+1
  #pragma unroll
  for (int layer = 0; layer < 2; ++layer){
    const unsigned short* wLT = layer ? w2T : w1T;
    const float* bL = layer ? b2 : b1;
    const bf16x8 a0 = load_h_frag(h16, tr*16 + lw, 0, rg);
    const bf16x8 a1 = load_h_frag(h16, tr*16 + lw, 32, rg);
    f32x4 cf[2];
    #pragma unroll
    for (int tcx = 0; tcx < 2; ++tcx){
      const int o = (tc0 + tcx)*16 + lw;
      const bf16x8 bf0 = *(const bf16x8*)(wLT + o*64 + rg*8);
      const bf16x8 bf1 = *(const bf16x8*)(wLT + o*64 + 32 + rg*8);
      const float bv = bL[o];
      f32x4 c = {bv, bv, bv, bv};
      c = __builtin_amdgcn_mfma_f32_16x16x32_bf16(a0, bf0, c, 0, 0, 0);
      c = __builtin_amdgcn_mfma_f32_16x16x32_bf16(a1, bf1, c, 0, 0, 0);
      cf[tcx] = c;
    }
    __syncthreads();   // all frag reads done before overwrite
    #pragma unroll
    for (int tcx = 0; tcx < 2; ++tcx)
      #pragma unroll
      for (int i = 0; i < 4; ++i)
        h16[(tr*16 + rg*4 + i)*HPAD + (tc0 + tcx)*16 + lw] = f2b(silu_f(cf[tcx][i]));
    __syncthreads();
  }

  // ---- A-fragments of final h for the W-GEMM (held across all paths) ----
  const int ch = wid & 1, r0 = (wid >> 1) * 16;
  const bf16x8 ha0 = load_h_frag(h16, r0 + lw, 0, rg);
  const bf16x8 ha1 = load_h_frag(h16, r0 + lw, 32, rg);

  float acc[9][4];
  #pragma unroll
  for (int q = 0; q < 9; ++q)
    #pragma unroll
    for (int i = 0; i < 4; ++i) acc[q][i] = 0.0f;
  __syncthreads();   // emb (tmp region) dead; x1 gather complete for all waves

  //        <P, D1,D2,D3, QB, COFF, XOFF, SHO>
  path_step<0, 1,1,1, 0,   0,  0, 0>(K, S, x16, w3T, b3, ha0, ha1, acc);
  path_step<1, 1,3,3, 1,   1,  0, 1>(K, S, x16, w3T, b3, ha0, ha1, acc);
  path_step<2, 1,5,5, 4,  10,  0, 4>(K, S, x16, w3T, b3, ha0, ha1, acc);
  path_step<3, 3,1,3, 1,  35, 16, 0>(K, S, x16, w3T, b3, ha0, ha1, acc);
  path_step<4, 3,3,1, 0,  44, 16, 1>(K, S, x16, w3T, b3, ha0, ha1, acc);
  path_step<5, 3,3,5, 4,  53, 16, 1>(K, S, x16, w3T, b3, ha0, ha1, acc);
  path_step<6, 3,5,3, 1,  98, 16, 4>(K, S, x16, w3T, b3, ha0, ha1, acc);
  path_step<7, 5,1,5, 4, 143, 64, 0>(K, S, x16, w3T, b3, ha0, ha1, acc);
  path_step<8, 5,3,3, 1, 168, 64, 1>(K, S, x16, w3T, b3, ha0, ha1, acc);
  path_step<9, 5,5,1, 0, 213, 64, 4>(K, S, x16, w3T, b3, ha0, ha1, acc);
  path_step<10,5,5,5, 4, 238, 64, 4>(K, S, x16, w3T, b3, ha0, ha1, acc);

  // ---- emit ----
  if (TWOPASS){
    // two rounds of 32 edges staged through the tmp region ([32][144] f32)
    float* stage = S + O_TP;
    #pragma unroll
    for (int rnd = 0; rnd < 2; ++rnd){
      const bool mine = ((r0 >> 5) == rnd);
      const int eb = r0 & 31;
      if (ch == 1 && mine){
        #pragma unroll
        for (int q = 0; q < 9; ++q)
          #pragma unroll
          for (int i = 0; i < 4; ++i)
            stage[(eb + rg*4 + i)*INDIM + q*16 + lw] = acc[q][i];
      }
      __syncthreads();
      if (ch == 0 && mine){
        #pragma unroll
        for (int q = 0; q < 9; ++q)
          #pragma unroll
          for (int i = 0; i < 4; ++i)
            stage[(eb + rg*4 + i)*INDIM + q*16 + lw] += acc[q][i];
      }
      __syncthreads();
      for (int idx = t; idx < 32*36; idx += 512){
        const int e = idx / 36, c4 = idx - e*36;
        *(float4*)(msg_or_out + (size_t)(e0 + rnd*32 + e)*INDIM + c4*4) =
            *(const float4*)(stage + e*INDIM + c4*4);
      }
      if (rnd == 0) __syncthreads();
    }
  } else {
    #pragma unroll
    for (int i = 0; i < 4; ++i){
      const int e = r0 + rg*4 + i;
      float* op = msg_or_out + (size_t)s_dst[e]*INDIM + lw;
      #pragma unroll
      for (int q = 0; q < 9; ++q) atomicAdd(op + q*16, acc[q][i]);
    }
  }
}

// ---------------- weight conversion: w3T [2816][64], w1T/w2T [64][64] (all bf16) ----------------
__global__ __launch_bounds__(256)
void w_cvt(const float* __restrict__ w3, const float* __restrict__ w1,
           const float* __restrict__ w2, unsigned short* __restrict__ wT){
  const int id = blockIdx.x*256 + threadIdx.x;
  if (id < 180224){
    const int n = id >> 6, k = id & 63;
    wT[id] = f2b(w3[(size_t)k*2816 + n]);
  } else if (id < 184320){
    const int j = id - 180224; const int o = j >> 6, c = j & 63;
    wT[id] = f2b(w1[c*64 + o]);
  } else if (id < 188416){
    const int j = id - 184320; const int o = j >> 6, c = j & 63;
    wT[id] = f2b(w2[c*64 + o]);
  }
}

// ---------------- scatter infrastructure ----------------
__global__ __launch_bounds__(256)
void e3_hist(const int* __restrict__ edst, int* __restrict__ cnt){
  int e = blockIdx.x*256 + threadIdx.x;
  if (e < NEDGES) atomicAdd(&cnt[edst[e]], 1);
}

__global__ __launch_bounds__(1024)
void e3_scan(const int* __restrict__ cnt, int* __restrict__ offs, int* __restrict__ cursor, int n){
  __shared__ int buf[1024];
  __shared__ int carry;
  const int t = threadIdx.x;
  if (t == 0) carry = 0;
  __syncthreads();
  for (int base = 0; base < n; base += 1024){
    int v = (base + t < n) ? cnt[base + t] : 0;
    buf[t] = v;
    __syncthreads();
    for (int d = 1; d < 1024; d <<= 1){
      int x = (t >= d) ? buf[t - d] : 0;
      __syncthreads();
      buf[t] += x;
      __syncthreads();
    }
    const int base_c = carry;
    if (base + t < n){
      const int ex = base_c + buf[t] - v;
      offs[base + t]   = ex;
      cursor[base + t] = ex;
    }
    __syncthreads();
    if (t == 1023) carry = base_c + buf[1023];
    __syncthreads();
  }
  if (t == 0) offs[n] = carry;
}

__global__ __launch_bounds__(256)
void e3_fill(const int* __restrict__ edst, int* __restrict__ cursor, int* __restrict__ eidx){
  int e = blockIdx.x*256 + threadIdx.x;
  if (e < NEDGES){
    int pos = atomicAdd(&cursor[edst[e]], 1);
    eidx[pos] = e;
  }
}

__global__ __launch_bounds__(192)
void e3_reduce(const float* __restrict__ msg, const int* __restrict__ offs,
               const int* __restrict__ eidx, float* __restrict__ out){
  const int nid = blockIdx.x;
  const int t = threadIdx.x;
  if (t >= 144) return;
  const int beg = offs[nid], end = offs[nid + 1];
  float a0 = 0.f, a1 = 0.f, a2 = 0.f, a3 = 0.f;
  int i = beg;
  for (; i + 4 <= end; i += 4){
    const int i0 = eidx[i], i1 = eidx[i+1], i2 = eidx[i+2], i3 = eidx[i+3];
    a0 += msg[(size_t)i0*INDIM + t];
    a1 += msg[(size_t)i1*INDIM + t];
    a2 += msg[(size_t)i2*INDIM + t];
    a3 += msg[(size_t)i3*INDIM + t];
  }
  for (; i < end; ++i) a0 += msg[(size_t)eidx[i]*INDIM + t];
  const float deg = (float)(end - beg);
  out[(size_t)nid*INDIM + t] = (a0 + a1 + a2 + a3) / fmaxf(deg, 1.0f);
}

__global__ __launch_bounds__(256)
void e3_div(float* __restrict__ out, const int* __restrict__ cnt, int n){
  int i = blockIdx.x*256 + threadIdx.x;
  if (i < n){
    float c = (float)cnt[i / INDIM];
    out[i] /= fmaxf(c, 1.0f);
  }
}

extern "C" void kernel_launch(void* const* d_in, const int* in_sizes, int n_in,
                              void* d_out, int out_size, void* d_ws, size_t ws_size,
                              hipStream_t stream)
{
  const float* f_in   = (const float*)d_in[0];
  const float* pos    = (const float*)d_in[1];
  const int*   batch  = (const int*)  d_in[3];
  const int*   esrc   = (const int*)  d_in[4];
  const int*   edst   = (const int*)  d_in[5];
  const float* eshift = (const float*)d_in[6];
  const float* cell   = (const float*)d_in[7];
  const float* w0 = (const float*)d_in[8];  const float* b0 = (const float*)d_in[9];
  const float* w1 = (const float*)d_in[10]; const float* b1 = (const float*)d_in[11];
  const float* w2 = (const float*)d_in[12]; const float* b2 = (const float*)d_in[13];
  const float* w3 = (const float*)d_in[14]; const float* b3 = (const float*)d_in[15];
  float* out = (float*)d_out;

  const size_t need = (1u << 20) + (size_t)NEDGES * INDIM * sizeof(float);
  const bool twopass = ws_size >= need;

  TPConsts K = build_consts();

  if (twopass){
    int* cnt_i  = (int*)d_ws;
    int* offs   = (int*)d_ws + 16384;
    int* cursor = (int*)d_ws + 32768;
    int* eidx   = (int*)d_ws + 49152;
    float* msg  = (float*)((char*)d_ws + (1u << 20));
    unsigned short* wT = (unsigned short*)d_out;   // dead until e3_reduce overwrites

    w_cvt<<<736, 256, 0, stream>>>(w3, w1, w2, wT);
    hipMemsetAsync(cnt_i, 0, 10240 * sizeof(int), stream);
    e3_hist<<<(NEDGES + 255)/256, 256, 0, stream>>>(edst, cnt_i);
    e3_scan<<<1, 1024, 0, stream>>>(cnt_i, offs, cursor, NNODES);
    e3_fill<<<(NEDGES + 255)/256, 256, 0, stream>>>(edst, cursor, eidx);
    e3_fused<true><<<NEDGES/EB, 512, 0, stream>>>(K,
        f_in, pos, batch, esrc, edst, eshift, cell,
        w0, b0, b1, b2, b3, wT, msg);
    e3_reduce<<<NNODES, 192, 0, stream>>>(msg, offs, eidx, out);
  } else {
    unsigned short* wT = (unsigned short*)d_ws;            // 376832 B
    int* cnt_i = (int*)((char*)d_ws + 376832);

    w_cvt<<<736, 256, 0, stream>>>(w3, w1, w2, wT);
    hipMemsetAsync(cnt_i, 0, NNODES * sizeof(int), stream);
    e3_hist<<<(NEDGES + 255)/256, 256, 0, stream>>>(edst, cnt_i);
    hipMemsetAsync(d_out, 0, (size_t)out_size * sizeof(float), stream);
    e3_fused<false><<<NEDGES/EB, 512, 0, stream>>>(K,
        f_in, pos, batch, esrc, edst, eshift, cell,
        w0, b0, b1, b2, b3, wT, out);
    e3_div<<<(out_size + 255)/256, 256, 0, stream>>>(out, cnt_i, out_size);
  }
}